// Round 1
// baseline (666.969 us; speedup 1.0000x reference)
//
#include <hip/hip_runtime.h>
#include <hip/hip_bf16.h>

typedef unsigned short u16;
typedef unsigned int u32;
typedef __attribute__((ext_vector_type(8))) short short8;
typedef __attribute__((ext_vector_type(4))) float f4;
typedef __attribute__((ext_vector_type(4))) u32 u4;

#define MFMA(a, b, c) __builtin_amdgcn_mfma_f32_16x16x32_bf16((a), (b), (c), 0, 0, 0)

// ---- constants ----
#define TT 256
#define BB 1024
#define NN (TT * BB)          // 262144 rows
// ws layout in u16 units:
#define WS_HID3 0             // N*128 bf16 frag-order, block-major: ((bI*256+t)*4+kc)*64+lane u4s
#define WS_WF   (NN * 128)    // 33554432
#define OFF_W1  0
#define OFF_W2  16384
#define OFF_W3  20480
#define OFF_WIH 24576
#define OFF_WHH 90112
#define OFF_WA  155648
#define WF_TOT  159744

static __device__ __forceinline__ u16 f2bf(float f) {
    u32 u = __float_as_uint(f);
    u32 r = (u + 0x7FFFu + ((u >> 16) & 1u)) >> 16;
    return (u16)r;
}
static __device__ __forceinline__ short8 pack8(f4 a, f4 b) {
    short8 r;
    r[0] = (short)f2bf(a[0]); r[1] = (short)f2bf(a[1]);
    r[2] = (short)f2bf(a[2]); r[3] = (short)f2bf(a[3]);
    r[4] = (short)f2bf(b[0]); r[5] = (short)f2bf(b[1]);
    r[6] = (short)f2bf(b[2]); r[7] = (short)f2bf(b[3]);
    return r;
}
static __device__ __forceinline__ short8 u4_to_s8(u4 v) {
    union { u4 u; short8 s; } t; t.u = v; return t.s;
}
static __device__ __forceinline__ float sigf(float x) {
    return __builtin_amdgcn_rcpf(1.f + __builtin_amdgcn_exp2f(-1.442695040888963f * x));
}
static __device__ __forceinline__ float tanhf_fast(float x) {
    return 2.f * __builtin_amdgcn_rcpf(1.f + __builtin_amdgcn_exp2f(-2.885390081777927f * x)) - 1.f;
}

// ---------------- K0: convert weights fp32 -> bf16 fragment order ----------------
static __device__ void convW128(const float* src, int Nn, u16* dst, int tid, int nth) {
    int tot = Nn * 128;
    for (int d = tid; d < tot; d += nth) {
        int j = d & 7, l = (d >> 3) & 63, ck = d >> 9;
        int kc = ck & 3, nt = ck >> 2;
        int n = nt * 16 + (l & 15), k = kc * 32 + ((l >> 4) << 3) + j;
        dst[d] = f2bf(src[n * 128 + k]);
    }
}
static __device__ void convW32(const float* src, int Nn, u16* dst, int tid, int nth) {
    int tot = Nn * 32;
    for (int d = tid; d < tot; d += nth) {
        int j = d & 7, l = (d >> 3) & 63, nt = d >> 9;
        int n = nt * 16 + (l & 15), k = ((l >> 4) << 3) + j;
        dst[d] = f2bf(src[n * 32 + k]);
    }
}

__global__ void k0_conv(const float* __restrict__ W1, const float* __restrict__ W2,
                        const float* __restrict__ W3, const float* __restrict__ Wih,
                        const float* __restrict__ Whh, const float* __restrict__ Wa,
                        const float* __restrict__ Wc, u16* __restrict__ wf) {
    int tid = blockIdx.x * blockDim.x + threadIdx.x;
    int nth = gridDim.x * blockDim.x;
    convW128(W1, 128, wf + OFF_W1, tid, nth);
    convW128(W2, 32, wf + OFF_W2, tid, nth);
    convW32(W3, 128, wf + OFF_W3, tid, nth);
    convW128(Wih, 512, wf + OFF_WIH, tid, nth);
    convW128(Whh, 512, wf + OFF_WHH, tid, nth);
    // WaWc: padded 32 x 128: rows 0..17 = Wa, 18 = Wc, 19..31 = 0
    for (int d = tid; d < 32 * 128; d += nth) {
        int j = d & 7, l = (d >> 3) & 63, ck = d >> 9;
        int kc = ck & 3, nt = ck >> 2;
        int n = nt * 16 + (l & 15), k = kc * 32 + ((l >> 4) << 3) + j;
        float v = (n < 18) ? Wa[n * 128 + k] : ((n == 18) ? Wc[k] : 0.f);
        wf[OFF_WA + d] = f2bf(v);
    }
}

// ---------------- Fused: encoder prelude + LSTM scan + heads ----------------
// 64 blocks x 512 thr. Block bI owns batch rows [bI*16, bI*16+16) for all t.
__global__ __launch_bounds__(512) void k_fused(
    const float* __restrict__ x, const float* __restrict__ b1, const float* __restrict__ b2,
    const float* __restrict__ b3, const u16* __restrict__ wf, u16* __restrict__ hid3,
    const float* __restrict__ bih, const float* __restrict__ bhh,
    const float* __restrict__ done, const float* __restrict__ h0, const float* __restrict__ c0,
    const float* __restrict__ ba, const float* __restrict__ bc, float* __restrict__ out) {
    // 40 KB: prelude per-wave scratch (8 x 2560 u16); loop aliases hbuf (8KB) + dls (16KB)
    __shared__ __align__(16) u16 smem[8 * 2560];

    int tid = threadIdx.x, wv = tid >> 6, lane = tid & 63;
    int m = lane & 15, q = lane >> 4;
    int bI = blockIdx.x;

    // ======== Phase 1: encoder prelude — each wave encodes its own chunks ========
    {
        u16* s1 = smem + wv * 2560;
        u16* s2 = s1 + 2048;
        const short8* W1v = (const short8*)(wf + OFF_W1);
        const short8* W2v = (const short8*)(wf + OFF_W2);
        const short8* W3v = (const short8*)(wf + OFF_W3);
        // reverse-t order so the loop's first chunks are freshest in L2
        for (int tt = 31; tt >= 0; --tt) {
            int t = tt * 8 + wv;
            const float* xr = x + ((size_t)t * 1024 + bI * 16 + m) * 128 + q * 8;
            short8 a1[4];
#pragma unroll
            for (int kc = 0; kc < 4; ++kc) {
                f4 f0 = *(const f4*)(xr + kc * 32);
                f4 f1 = *(const f4*)(xr + kc * 32 + 4);
                a1[kc] = pack8(f0, f1);
            }
            // Layer 1: 128 -> 128
#pragma unroll
            for (int nt = 0; nt < 8; ++nt) {
                f4 acc = {0.f, 0.f, 0.f, 0.f};
#pragma unroll
                for (int kc = 0; kc < 4; ++kc) acc = MFMA(a1[kc], W1v[(nt * 4 + kc) * 64 + lane], acc);
                int col = nt * 16 + m;
                float bb = b1[col];
                int base = (col >> 5) * 512 + ((col >> 3) & 3) * 128 + (col & 7);
#pragma unroll
                for (int p = 0; p < 4; ++p) {
                    float v = acc[p] + bb; v = v > 0.f ? v : 0.f;
                    s1[base + (q * 4 + p) * 8] = f2bf(v);
                }
            }
            asm volatile("s_waitcnt lgkmcnt(0)" ::: "memory");  // within-wave scr dependency
            short8 a2[4];
#pragma unroll
            for (int kc = 0; kc < 4; ++kc) a2[kc] = *(const short8*)(s1 + kc * 512 + lane * 8);
            // Layer 2: 128 -> 32
#pragma unroll
            for (int nt = 0; nt < 2; ++nt) {
                f4 acc = {0.f, 0.f, 0.f, 0.f};
#pragma unroll
                for (int kc = 0; kc < 4; ++kc) acc = MFMA(a2[kc], W2v[(nt * 4 + kc) * 64 + lane], acc);
                int col = nt * 16 + m;
                float bb = b2[col];
                int base = (col >> 3) * 128 + (col & 7);
#pragma unroll
                for (int p = 0; p < 4; ++p) {
                    float v = acc[p] + bb; v = v > 0.f ? v : 0.f;
                    s2[base + (q * 4 + p) * 8] = f2bf(v);
                }
            }
            asm volatile("s_waitcnt lgkmcnt(0)" ::: "memory");
            short8 a3 = *(const short8*)(s2 + lane * 8);
            // Layer 3: 32 -> 128
#pragma unroll
            for (int nt = 0; nt < 8; ++nt) {
                f4 acc = {0.f, 0.f, 0.f, 0.f};
                acc = MFMA(a3, W3v[nt * 64 + lane], acc);
                int col = nt * 16 + m;
                float bb = b3[col];
                int base = (col >> 5) * 512 + ((col >> 3) & 3) * 128 + (col & 7);
#pragma unroll
                for (int p = 0; p < 4; ++p) {
                    float v = acc[p] + bb; v = v > 0.f ? v : 0.f;
                    s1[base + (q * 4 + p) * 8] = f2bf(v);
                }
            }
            asm volatile("s_waitcnt lgkmcnt(0)" ::: "memory");
            u4* dst = (u4*)hid3 + ((size_t)bI * 256 + t) * 256;
#pragma unroll
            for (int kc = 0; kc < 4; ++kc) dst[kc * 64 + lane] = *(const u4*)(s1 + kc * 512 + lane * 8);
        }
    }
    __syncthreads();  // full drain: prelude global writes + scr reuse

    // ======== Phase 2: init LSTM state (aliases smem) ========
    u16 (*hbuf)[2048] = (u16(*)[2048])smem;   // [2][2048] u16, double-buffered h frags
    float* dls = (float*)(smem + 4096);       // 4096 floats: (1-done) for 256 t x 16 rows

    int rb = bI * 16;
    for (int i = tid; i < 4096; i += 512) {
        int t = i >> 4, r = i & 15;
        dls[i] = 1.0f - done[(size_t)t * BB + rb + r];
    }
    int u = wv * 16 + m;  // this wave's hidden-unit column
    float cst[4];
#pragma unroll
    for (int k = 0; k < 4; ++k) {
        int r = 4 * q + k;
        cst[k] = c0[(size_t)(rb + r) * 128 + u];
        float hv = h0[(size_t)(rb + r) * 128 + u];
        hbuf[0][(u >> 5) * 512 + (((u >> 3) & 3) * 16 + r) * 8 + (u & 7)] = f2bf(hv);
    }
    const short8* WHv = (const short8*)(wf + OFF_WHH);
    const short8* WIv = (const short8*)(wf + OFF_WIH);
    const short8* WAv = (const short8*)(wf + OFF_WA);
    short8 wh[4][4], wi[4][4];
#pragma unroll
    for (int g = 0; g < 4; ++g)
#pragma unroll
        for (int kc = 0; kc < 4; ++kc) {
            int nt = g * 8 + wv;
            wh[g][kc] = WHv[(nt * 4 + kc) * 64 + lane];
            wi[g][kc] = WIv[(nt * 4 + kc) * 64 + lane];
        }
    float bg[4];
#pragma unroll
    for (int g = 0; g < 4; ++g) bg[g] = bih[g * 128 + u] + bhh[g * 128 + u];
    // head fragments (waves 0,1 only): wave wv handles head tile nt = wv
    short8 wab[4];
    float hb = 0.f;
    int hcol = wv * 16 + m;
    if (wv < 2) {
#pragma unroll
        for (int kc = 0; kc < 4; ++kc) wab[kc] = WAv[(wv * 4 + kc) * 64 + lane];
        if (hcol < 18) hb = ba[hcol];
        else if (hcol == 18) hb = bc[0];
    }
    const u4* h3 = (const u4*)hid3 + (size_t)bI * 65536;  // this block's chunk slice
    u4 xf[4];
#pragma unroll
    for (int kc = 0; kc < 4; ++kc) xf[kc] = h3[kc * 64 + lane];
    __syncthreads();

    // ======== Phase 3: the scan. Raw barrier: only lgkmcnt drained; vmcnt stays in flight ========
    for (int t = 0; t < TT; ++t) {
        const u16* hc = hbuf[t & 1];
        u16* hn = hbuf[(t + 1) & 1];
        short8 ah[4];
#pragma unroll
        for (int kc = 0; kc < 4; ++kc) ah[kc] = *(const short8*)(hc + kc * 512 + lane * 8);
        f4 aH[4], aX[4];
#pragma unroll
        for (int g = 0; g < 4; ++g) {
            aH[g] = (f4){0.f, 0.f, 0.f, 0.f};
            aX[g] = (f4){bg[g], bg[g], bg[g], bg[g]};  // bias folded into C-in
        }
#pragma unroll
        for (int kc = 0; kc < 4; ++kc) {
            short8 xs = u4_to_s8(xf[kc]);
#pragma unroll
            for (int g = 0; g < 4; ++g) {
                aH[g] = MFMA(ah[kc], wh[g][kc], aH[g]);
                aX[g] = MFMA(xs, wi[g][kc], aX[g]);
            }
        }
        if (t < TT - 1) {
#pragma unroll
            for (int kc = 0; kc < 4; ++kc)
                xf[kc] = h3[(size_t)(t + 1) * 256 + kc * 64 + lane];
        }
        // fused head for step t-1 (ah holds h_{t-1}); off the other waves' critical path
        if (wv < 2 && t > 0) {
            f4 hacc = {0.f, 0.f, 0.f, 0.f};
#pragma unroll
            for (int kc = 0; kc < 4; ++kc) hacc = MFMA(ah[kc], wab[kc], hacc);
            if (hcol < 19) {
                size_t n0 = (size_t)(t - 1) * 1024 + rb + 4 * q;
#pragma unroll
                for (int p = 0; p < 4; ++p) out[(n0 + p) * 19 + hcol] = hacc[p] + hb;
            }
        }
        f4 dm = *(const f4*)(dls + t * 16 + 4 * q);
#pragma unroll
        for (int k = 0; k < 4; ++k) {
            float mm = dm[k];
            float ip = aX[0][k] + mm * aH[0][k];
            float fp = aX[1][k] + mm * aH[1][k];
            float gp = aX[2][k] + mm * aH[2][k];
            float op = aX[3][k] + mm * aH[3][k];
            float ii = sigf(ip), ff = sigf(fp), gg = tanhf_fast(gp), oo = sigf(op);
            float cc = ff * (mm * cst[k]) + ii * gg;
            cst[k] = cc;
            float hh = oo * tanhf_fast(cc);
            hn[(u >> 5) * 512 + (((u >> 3) & 3) * 16 + (4 * q + k)) * 8 + (u & 7)] = f2bf(hh);
        }
        // barrier needs ONLY the LDS writes drained; xf prefetch + out stores stay in flight
        asm volatile("s_waitcnt lgkmcnt(0)" ::: "memory");
        __builtin_amdgcn_s_barrier();
        asm volatile("" ::: "memory");
    }
    // final head: t_out = 255, h_255 lives in hbuf[0] (written at t=255, barrier passed)
    if (wv < 2) {
        short8 ah[4];
#pragma unroll
        for (int kc = 0; kc < 4; ++kc) ah[kc] = *(const short8*)(hbuf[0] + kc * 512 + lane * 8);
        f4 hacc = {0.f, 0.f, 0.f, 0.f};
#pragma unroll
        for (int kc = 0; kc < 4; ++kc) hacc = MFMA(ah[kc], wab[kc], hacc);
        if (hcol < 19) {
            size_t n0 = (size_t)255 * 1024 + rb + 4 * q;
#pragma unroll
            for (int p = 0; p < 4; ++p) out[(n0 + p) * 19 + hcol] = hacc[p] + hb;
        }
    }
}

extern "C" void kernel_launch(void* const* d_in, const int* in_sizes, int n_in,
                              void* d_out, int out_size, void* d_ws, size_t ws_size,
                              hipStream_t stream) {
    const float* x    = (const float*)d_in[0];
    const float* done = (const float*)d_in[1];
    const float* h0   = (const float*)d_in[2];
    const float* c0   = (const float*)d_in[3];
    const float* W1   = (const float*)d_in[4];
    const float* b1   = (const float*)d_in[5];
    const float* W2   = (const float*)d_in[6];
    const float* b2   = (const float*)d_in[7];
    const float* W3   = (const float*)d_in[8];
    const float* b3   = (const float*)d_in[9];
    const float* Wih  = (const float*)d_in[10];
    const float* Whh  = (const float*)d_in[11];
    const float* bih  = (const float*)d_in[12];
    const float* bhh  = (const float*)d_in[13];
    const float* Wa   = (const float*)d_in[14];
    const float* ba   = (const float*)d_in[15];
    const float* Wc   = (const float*)d_in[16];
    const float* bc   = (const float*)d_in[17];
    float* out = (float*)d_out;

    u16* ws = (u16*)d_ws;
    u16* hid3f = ws + WS_HID3;   // 67.1 MB, block-major chunk layout
    u16* wf    = ws + WS_WF;     // 312 KB converted weights
    // total ws needed: (33554432 + 159744) * 2 = 67,428,352 bytes

    hipLaunchKernelGGL(k0_conv, dim3(128), dim3(256), 0, stream,
                       W1, W2, W3, Wih, Whh, Wa, Wc, wf);
    hipLaunchKernelGGL(k_fused, dim3(64), dim3(512), 0, stream,
                       x, b1, b2, b3, wf, hid3f, bih, bhh, done, h0, c0, ba, bc, out);
}

// Round 2
// 532.764 us; speedup vs baseline: 1.2519x; 1.2519x over previous
//
#include <hip/hip_runtime.h>
#include <hip/hip_bf16.h>

typedef unsigned short u16;
typedef unsigned int u32;
typedef __attribute__((ext_vector_type(8))) short short8;
typedef __attribute__((ext_vector_type(4))) float f4;
typedef __attribute__((ext_vector_type(4))) u32 u4;

#define MFMA(a, b, c) __builtin_amdgcn_mfma_f32_16x16x32_bf16((a), (b), (c), 0, 0, 0)

// ---- constants ----
#define TT 256
#define BB 1024
#define NN (TT * BB)          // 262144 rows
#define L2E 1.442695040888963f
// ws layout in u16 units:
#define WS_HID3 0             // N*128 bf16 frag-order, block-major: ((bI*256+t)*4+kc)*64+lane u4s
#define WS_WF   (NN * 128)    // 33554432
#define OFF_W1  0
#define OFF_W2  16384
#define OFF_W3  20480
#define OFF_WIH 24576
#define OFF_WHH 90112
#define OFF_WA  155648
#define WF_TOT  159744

static __device__ __forceinline__ u16 f2bf(float f) {
    u32 u = __float_as_uint(f);
    u32 r = (u + 0x7FFFu + ((u >> 16) & 1u)) >> 16;
    return (u16)r;
}
static __device__ __forceinline__ short8 pack8(f4 a, f4 b) {
    short8 r;
    r[0] = (short)f2bf(a[0]); r[1] = (short)f2bf(a[1]);
    r[2] = (short)f2bf(a[2]); r[3] = (short)f2bf(a[3]);
    r[4] = (short)f2bf(b[0]); r[5] = (short)f2bf(b[1]);
    r[6] = (short)f2bf(b[2]); r[7] = (short)f2bf(b[3]);
    return r;
}
static __device__ __forceinline__ short8 u4_to_s8(u4 v) {
    union { u4 u; short8 s; } t; t.u = v; return t.s;
}
// pre-scaled logistic: expects x already multiplied by log2(e) (folded into W/b)
static __device__ __forceinline__ float sig_pre(float x) {
    return __builtin_amdgcn_rcpf(1.f + __builtin_amdgcn_exp2f(-x));
}
static __device__ __forceinline__ float tanhf_fast(float x) {
    return 2.f * __builtin_amdgcn_rcpf(1.f + __builtin_amdgcn_exp2f(-2.885390081777927f * x)) - 1.f;
}

// ---------------- K0: convert weights fp32 -> bf16 fragment order ----------------
static __device__ void convW128(const float* src, int Nn, u16* dst, int tid, int nth) {
    int tot = Nn * 128;
    for (int d = tid; d < tot; d += nth) {
        int j = d & 7, l = (d >> 3) & 63, ck = d >> 9;
        int kc = ck & 3, nt = ck >> 2;
        int n = nt * 16 + (l & 15), k = kc * 32 + ((l >> 4) << 3) + j;
        dst[d] = f2bf(src[n * 128 + k]);
    }
}
// gate-weight variant: rows scaled by log2e (gates i,f,o) or 2*log2e (gate g)
static __device__ void convW128g(const float* src, u16* dst, int tid, int nth) {
    int tot = 512 * 128;
    for (int d = tid; d < tot; d += nth) {
        int j = d & 7, l = (d >> 3) & 63, ck = d >> 9;
        int kc = ck & 3, nt = ck >> 2;
        int n = nt * 16 + (l & 15), k = kc * 32 + ((l >> 4) << 3) + j;
        float sc = ((n >> 7) == 2) ? (2.f * L2E) : L2E;
        dst[d] = f2bf(src[n * 128 + k] * sc);
    }
}
static __device__ void convW32(const float* src, int Nn, u16* dst, int tid, int nth) {
    int tot = Nn * 32;
    for (int d = tid; d < tot; d += nth) {
        int j = d & 7, l = (d >> 3) & 63, nt = d >> 9;
        int n = nt * 16 + (l & 15), k = ((l >> 4) << 3) + j;
        dst[d] = f2bf(src[n * 32 + k]);
    }
}

__global__ void k0_conv(const float* __restrict__ W1, const float* __restrict__ W2,
                        const float* __restrict__ W3, const float* __restrict__ Wih,
                        const float* __restrict__ Whh, const float* __restrict__ Wa,
                        const float* __restrict__ Wc, u16* __restrict__ wf) {
    int tid = blockIdx.x * blockDim.x + threadIdx.x;
    int nth = gridDim.x * blockDim.x;
    convW128(W1, 128, wf + OFF_W1, tid, nth);
    convW128(W2, 32, wf + OFF_W2, tid, nth);
    convW32(W3, 128, wf + OFF_W3, tid, nth);
    convW128g(Wih, wf + OFF_WIH, tid, nth);
    convW128g(Whh, wf + OFF_WHH, tid, nth);
    // WaWc: padded 32 x 128: rows 0..17 = Wa, 18 = Wc, 19..31 = 0
    for (int d = tid; d < 32 * 128; d += nth) {
        int j = d & 7, l = (d >> 3) & 63, ck = d >> 9;
        int kc = ck & 3, nt = ck >> 2;
        int n = nt * 16 + (l & 15), k = kc * 32 + ((l >> 4) << 3) + j;
        float v = (n < 18) ? Wa[n * 128 + k] : ((n == 18) ? Wc[k] : 0.f);
        wf[OFF_WA + d] = f2bf(v);
    }
}

// ---------------- K1: encoder (3 layers), full-GPU, block-major hid3 out ----------------
__global__ __launch_bounds__(256, 2) void k1_enc(
    const float* __restrict__ x, const float* __restrict__ b1, const float* __restrict__ b2,
    const float* __restrict__ b3, const u16* __restrict__ wf, u16* __restrict__ hid3f) {
    __shared__ __align__(16) u16 scr[4][2560];  // per-wave: 2048 (K=128 frag) + 512 (K=32 frag)

    int tid = threadIdx.x, wv = tid >> 6, lane = tid & 63;
    int m = lane & 15, q = lane >> 4;
    u16* s1 = scr[wv];
    u16* s2 = scr[wv] + 2048;
    const short8* W1v = (const short8*)(wf + OFF_W1);
    const short8* W2v = (const short8*)(wf + OFF_W2);
    const short8* W3v = (const short8*)(wf + OFF_W3);
    // hoist W1, W3 fragments into registers (W2 stays in-loop: 8KB, L1-resident)
    short8 w1r[32], w3r[8];
#pragma unroll
    for (int i = 0; i < 32; ++i) w1r[i] = W1v[i * 64 + lane];
#pragma unroll
    for (int i = 0; i < 8; ++i) w3r[i] = W3v[i * 64 + lane];
    int wid = blockIdx.x * 4 + wv;  // 2048 waves total

    for (int it = 0; it < 8; ++it) {
        int c = wid + it * 2048;    // chunk: rows [16c, 16c+16)
        short8 a1[4];
        const float* xr = x + (size_t)(c * 16 + m) * 128 + q * 8;
#pragma unroll
        for (int kc = 0; kc < 4; ++kc) {
            f4 f0 = *(const f4*)(xr + kc * 32);
            f4 f1 = *(const f4*)(xr + kc * 32 + 4);
            a1[kc] = pack8(f0, f1);
        }
        // Layer 1: 128 -> 128
#pragma unroll
        for (int nt = 0; nt < 8; ++nt) {
            f4 acc = {0.f, 0.f, 0.f, 0.f};
#pragma unroll
            for (int kc = 0; kc < 4; ++kc) acc = MFMA(a1[kc], w1r[nt * 4 + kc], acc);
            int col = nt * 16 + m;
            float bb = b1[col];
            int base = (col >> 5) * 512 + ((col >> 3) & 3) * 128 + (col & 7);
#pragma unroll
            for (int p = 0; p < 4; ++p) {
                float v = acc[p] + bb; v = v > 0.f ? v : 0.f;
                s1[base + (q * 4 + p) * 8] = f2bf(v);
            }
        }
        asm volatile("s_waitcnt lgkmcnt(0)" ::: "memory");  // scratch is wave-private
        short8 a2[4];
#pragma unroll
        for (int kc = 0; kc < 4; ++kc) a2[kc] = *(const short8*)(s1 + kc * 512 + lane * 8);
        // Layer 2: 128 -> 32
#pragma unroll
        for (int nt = 0; nt < 2; ++nt) {
            f4 acc = {0.f, 0.f, 0.f, 0.f};
#pragma unroll
            for (int kc = 0; kc < 4; ++kc) acc = MFMA(a2[kc], W2v[(nt * 4 + kc) * 64 + lane], acc);
            int col = nt * 16 + m;
            float bb = b2[col];
            int base = (col >> 3) * 128 + (col & 7);
#pragma unroll
            for (int p = 0; p < 4; ++p) {
                float v = acc[p] + bb; v = v > 0.f ? v : 0.f;
                s2[base + (q * 4 + p) * 8] = f2bf(v);
            }
        }
        asm volatile("s_waitcnt lgkmcnt(0)" ::: "memory");
        short8 a3 = *(const short8*)(s2 + lane * 8);
        // Layer 3: 32 -> 128
#pragma unroll
        for (int nt = 0; nt < 8; ++nt) {
            f4 acc = {0.f, 0.f, 0.f, 0.f};
            acc = MFMA(a3, w3r[nt], acc);
            int col = nt * 16 + m;
            float bb = b3[col];
            int base = (col >> 5) * 512 + ((col >> 3) & 3) * 128 + (col & 7);
#pragma unroll
            for (int p = 0; p < 4; ++p) {
                float v = acc[p] + bb; v = v > 0.f ? v : 0.f;
                s1[base + (q * 4 + p) * 8] = f2bf(v);
            }
        }
        asm volatile("s_waitcnt lgkmcnt(0)" ::: "memory");
        // block-major layout for the scan: chunk c -> (t = c>>6, bI = c&63)
        int bI = c & 63, tt = c >> 6;
        u4* dst = (u4*)hid3f + ((size_t)bI * 256 + tt) * 256;
#pragma unroll
        for (int kc = 0; kc < 4; ++kc) dst[kc * 64 + lane] = *(const u4*)(s1 + kc * 512 + lane * 8);
    }
}

// ---------------- K3: LSTM scan + fused heads (64 blocks x 512 thr) ----------------
// launch_bounds(512,1): grid=64 on 256 CUs -> never >1 block/CU; allow up to 512 VGPR
// so wh/wi/wab weight fragments stay register-resident (round-1 showed 128 VGPR =>
// the compiler was re-loading 256KB of gate weights from L2 every timestep).
__global__ __launch_bounds__(512, 1) void k3_scan(
    const u16* __restrict__ hid3, const u16* __restrict__ wf,
    const float* __restrict__ bih, const float* __restrict__ bhh,
    const float* __restrict__ done, const float* __restrict__ h0, const float* __restrict__ c0,
    const float* __restrict__ ba, const float* __restrict__ bc, float* __restrict__ out) {
    __shared__ __align__(16) u16 hbuf[2][2048];  // 16 rows x 128 bf16, frag order, dbl-buffered
    __shared__ __align__(16) float dls[4096];    // (1-done) for 256 t x 16 rows

    int tid = threadIdx.x, wv = tid >> 6, lane = tid & 63;
    int m = lane & 15, q = lane >> 4;
    int bI = blockIdx.x, rb = bI * 16;
    int u = wv * 16 + m;  // this wave's hidden-unit column

    const short8* WHv = (const short8*)(wf + OFF_WHH);
    const short8* WIv = (const short8*)(wf + OFF_WIH);
    const short8* WAv = (const short8*)(wf + OFF_WA);
    short8 wh[4][4], wi[4][4];  // resident gate-weight fragments (128 VGPR)
#pragma unroll
    for (int g = 0; g < 4; ++g)
#pragma unroll
        for (int kc = 0; kc < 4; ++kc) {
            int nt = g * 8 + wv;
            wh[g][kc] = WHv[(nt * 4 + kc) * 64 + lane];
            wi[g][kc] = WIv[(nt * 4 + kc) * 64 + lane];
        }
    // biases, pre-scaled to match the exp2-folded weights
    float bg[4];
#pragma unroll
    for (int g = 0; g < 4; ++g) {
        float sc = (g == 2) ? (2.f * L2E) : L2E;
        bg[g] = (bih[g * 128 + u] + bhh[g * 128 + u]) * sc;
    }
    // head fragments (waves 0,1): wave wv handles head tile nt = wv
    short8 wab[4];
    float hb = 0.f;
    int hcol = wv * 16 + m;
    if (wv < 2) {
#pragma unroll
        for (int kc = 0; kc < 4; ++kc) wab[kc] = WAv[(wv * 4 + kc) * 64 + lane];
        if (hcol < 18) hb = ba[hcol];
        else if (hcol == 18) hb = bc[0];
    }

    for (int i = tid; i < 4096; i += 512) {
        int t = i >> 4, r = i & 15;
        dls[i] = 1.0f - done[(size_t)t * BB + rb + r];
    }
    float cst[4];
#pragma unroll
    for (int k = 0; k < 4; ++k) {
        int r = 4 * q + k;
        cst[k] = c0[(size_t)(rb + r) * 128 + u];
        float hv = h0[(size_t)(rb + r) * 128 + u];
        hbuf[0][(u >> 5) * 512 + (((u >> 3) & 3) * 16 + r) * 8 + (u & 7)] = f2bf(hv);
    }
    const u4* h3 = (const u4*)hid3 + (size_t)bI * 65536;  // this block's chunk slice
    u4 xf[4];
#pragma unroll
    for (int kc = 0; kc < 4; ++kc) xf[kc] = h3[kc * 64 + lane];
    __syncthreads();

    // scan: raw barrier, only lgkmcnt drained; xf prefetch + out stores stay in flight
    for (int t = 0; t < TT; ++t) {
        const u16* hc = hbuf[t & 1];
        u16* hn = hbuf[(t + 1) & 1];
        short8 ah[4];
#pragma unroll
        for (int kc = 0; kc < 4; ++kc) ah[kc] = *(const short8*)(hc + kc * 512 + lane * 8);
        f4 aH[4], aX[4];
#pragma unroll
        for (int g = 0; g < 4; ++g) {
            aH[g] = (f4){0.f, 0.f, 0.f, 0.f};
            aX[g] = (f4){bg[g], bg[g], bg[g], bg[g]};  // bias folded into C-in
        }
#pragma unroll
        for (int kc = 0; kc < 4; ++kc) {
            short8 xs = u4_to_s8(xf[kc]);
#pragma unroll
            for (int g = 0; g < 4; ++g) {
                aH[g] = MFMA(ah[kc], wh[g][kc], aH[g]);
                aX[g] = MFMA(xs, wi[g][kc], aX[g]);
            }
        }
        if (t < TT - 1) {
#pragma unroll
            for (int kc = 0; kc < 4; ++kc)
                xf[kc] = h3[(size_t)(t + 1) * 256 + kc * 64 + lane];
        }
        // fused head for step t-1 (ah holds h_{t-1}); off the other waves' critical path
        if (wv < 2 && t > 0) {
            f4 hacc = {0.f, 0.f, 0.f, 0.f};
#pragma unroll
            for (int kc = 0; kc < 4; ++kc) hacc = MFMA(ah[kc], wab[kc], hacc);
            if (hcol < 19) {
                size_t n0 = (size_t)(t - 1) * 1024 + rb + 4 * q;
#pragma unroll
                for (int p = 0; p < 4; ++p) out[(n0 + p) * 19 + hcol] = hacc[p] + hb;
            }
        }
        f4 dm = *(const f4*)(dls + t * 16 + 4 * q);
#pragma unroll
        for (int k = 0; k < 4; ++k) {
            float mm = dm[k];
            float ip = aX[0][k] + mm * aH[0][k];   // pre-scaled by log2e
            float fp = aX[1][k] + mm * aH[1][k];
            float gp = aX[2][k] + mm * aH[2][k];   // pre-scaled by 2*log2e
            float op = aX[3][k] + mm * aH[3][k];
            float ii = sig_pre(ip), ff = sig_pre(fp), oo = sig_pre(op);
            float gg = 2.f * sig_pre(gp) - 1.f;    // tanh via pre-scaled sigmoid
            float cc = ff * (mm * cst[k]) + ii * gg;
            cst[k] = cc;
            float hh = oo * tanhf_fast(cc);
            hn[(u >> 5) * 512 + (((u >> 3) & 3) * 16 + (4 * q + k)) * 8 + (u & 7)] = f2bf(hh);
        }
        // barrier needs ONLY the LDS writes drained
        asm volatile("s_waitcnt lgkmcnt(0)" ::: "memory");
        __builtin_amdgcn_s_barrier();
        asm volatile("" ::: "memory");
    }
    // final head: t_out = 255, h_255 lives in hbuf[0]
    if (wv < 2) {
        short8 ah[4];
#pragma unroll
        for (int kc = 0; kc < 4; ++kc) ah[kc] = *(const short8*)(hbuf[0] + kc * 512 + lane * 8);
        f4 hacc = {0.f, 0.f, 0.f, 0.f};
#pragma unroll
        for (int kc = 0; kc < 4; ++kc) hacc = MFMA(ah[kc], wab[kc], hacc);
        if (hcol < 19) {
            size_t n0 = (size_t)255 * 1024 + rb + 4 * q;
#pragma unroll
            for (int p = 0; p < 4; ++p) out[(n0 + p) * 19 + hcol] = hacc[p] + hb;
        }
    }
}

extern "C" void kernel_launch(void* const* d_in, const int* in_sizes, int n_in,
                              void* d_out, int out_size, void* d_ws, size_t ws_size,
                              hipStream_t stream) {
    const float* x    = (const float*)d_in[0];
    const float* done = (const float*)d_in[1];
    const float* h0   = (const float*)d_in[2];
    const float* c0   = (const float*)d_in[3];
    const float* W1   = (const float*)d_in[4];
    const float* b1   = (const float*)d_in[5];
    const float* W2   = (const float*)d_in[6];
    const float* b2   = (const float*)d_in[7];
    const float* W3   = (const float*)d_in[8];
    const float* b3   = (const float*)d_in[9];
    const float* Wih  = (const float*)d_in[10];
    const float* Whh  = (const float*)d_in[11];
    const float* bih  = (const float*)d_in[12];
    const float* bhh  = (const float*)d_in[13];
    const float* Wa   = (const float*)d_in[14];
    const float* ba   = (const float*)d_in[15];
    const float* Wc   = (const float*)d_in[16];
    const float* bc   = (const float*)d_in[17];
    float* out = (float*)d_out;

    u16* ws = (u16*)d_ws;
    u16* hid3f = ws + WS_HID3;   // 67.1 MB, block-major chunk layout
    u16* wf    = ws + WS_WF;     // 312 KB converted weights
    // total ws needed: (33554432 + 159744) * 2 = 67,428,352 bytes

    hipLaunchKernelGGL(k0_conv, dim3(128), dim3(256), 0, stream,
                       W1, W2, W3, Wih, Whh, Wa, Wc, wf);
    hipLaunchKernelGGL(k1_enc, dim3(512), dim3(256), 0, stream,
                       x, b1, b2, b3, wf, hid3f);
    hipLaunchKernelGGL(k3_scan, dim3(64), dim3(512), 0, stream,
                       hid3f, wf, bih, bhh, done, h0, c0, ba, bc, out);
}